// Round 7
// baseline (37.769 us; speedup 1.0000x reference)
//
#include <hip/hip_runtime.h>

#define S7 7
#define NCELL 49            // S*S
#define CH 30
#define IMG_F (CH * NCELL)  // 1470 floats per image
#define K_IMG 2             // images per tile
#define BLK 512             // 8 waves/block
#define NF4 (K_IMG * IMG_F / 4)  // 735 float4 per tensor per tile
#define GRID 768            // persistent: 3 blocks/CU (2 x 23.5KB LDS = 47KB) * 256 CU

typedef __attribute__((address_space(1))) const void global_cvoid;
typedef __attribute__((address_space(3))) void lds_void;

__global__ __launch_bounds__(BLK) void yolo_loss_stage1(
    const float4* __restrict__ pred4,
    const float4* __restrict__ lab4,
    float* __restrict__ partials,
    int npairs)
{
    // double-buffered tiles
    __shared__ float4 sp4[2][NF4];
    __shared__ float4 sl4[2][NF4];

    const int tid = threadIdx.x;
    const int wid = tid >> 6;
    float contrib = 0.0f;

    // per-wave gl_lds count per tile: stage loop iter k=0 hits all waves,
    // k=1 (i = tid+512 < 735) hits tid<223 -> waves 0-3 only (wave 3 partial
    // exec still issues the instruction). So waves 0-3: 4 loads/tile, 4-7: 2.
    #define STAGE(buf, pair)                                                     \
        do {                                                                     \
            const size_t g4_ = (size_t)(pair) * NF4;                             \
            for (int i_ = tid; i_ < NF4; i_ += BLK) {                            \
                __builtin_amdgcn_global_load_lds(                                \
                    (global_cvoid*)(pred4 + g4_ + i_),                           \
                    (lds_void*)(&sp4[buf][i_]), 16, 0, 0);                       \
                __builtin_amdgcn_global_load_lds(                                \
                    (global_cvoid*)(lab4 + g4_ + i_),                            \
                    (lds_void*)(&sl4[buf][i_]), 16, 0, 0);                       \
            }                                                                    \
        } while (0)

    const int bid = (int)blockIdx.x;
    const int ntiles = (npairs - bid + GRID - 1) / GRID;   // uniform per block

    // prologue: stage tile 0 into buf 0
    STAGE(0, bid);

    for (int t = 0; t < ntiles; ++t) {
        const int cur = t & 1;
        const bool hasnext = (t + 1) < ntiles;

        if (hasnext)
            STAGE(cur ^ 1, bid + (t + 1) * GRID);

        // counted vmcnt: wait only for tile t's loads, keep tile t+1's in flight
        if (hasnext) {
            if (wid < 4) asm volatile("s_waitcnt vmcnt(4)" ::: "memory");
            else         asm volatile("s_waitcnt vmcnt(2)" ::: "memory");
        } else {
            asm volatile("s_waitcnt vmcnt(0)" ::: "memory");
        }
        __builtin_amdgcn_sched_barrier(0);
        __builtin_amdgcn_s_barrier();   // all waves' tile-t data visible in LDS

        // ---- compute: one thread per cell (98 of 512) ----
        if (tid < K_IMG * NCELL) {
            const float* __restrict__ sp = (const float*)sp4[cur];
            const float* __restrict__ sl = (const float*)sl4[cur];
            const int img  = tid / NCELL;
            const int cell = tid - img * NCELL;
            const float* __restrict__ pb = sp + img * IMG_F + cell;
            const float* __restrict__ lb = sl + img * IMG_F + cell;

            float p[10], l[10];
            #pragma unroll
            for (int c = 0; c < 10; ++c) {
                p[c] = pb[c * NCELL];
                l[c] = lb[c * NCELL];
            }
            float cls = 0.0f;
            #pragma unroll
            for (int c = 10; c < CH; ++c) {
                float d = pb[c * NCELL] - lb[c * NCELL];
                cls += d * d;
            }

            const int   row = cell / S7;
            const float mi = (float)row;
            const float nj = (float)(cell - row * S7);
            const float invS = 1.0f / 7.0f;

            float ax1, ay1, ax2, ay2;
            {
                float cx = (p[0] + mi) * invS, cy = (p[1] + nj) * invS;
                ax1 = cx - 0.5f * p[2]; ay1 = cy - 0.5f * p[3];
                ax2 = cx + 0.5f * p[2]; ay2 = cy + 0.5f * p[3];
            }
            float bx1, by1, bx2, by2;
            {
                float cx = (p[5] + mi) * invS, cy = (p[6] + nj) * invS;
                bx1 = cx - 0.5f * p[7]; by1 = cy - 0.5f * p[8];
                bx2 = cx + 0.5f * p[7]; by2 = cy + 0.5f * p[8];
            }
            float gx1, gy1, gx2, gy2;
            {
                float cx = (l[0] + mi) * invS, cy = (l[1] + nj) * invS;
                gx1 = cx - 0.5f * l[2]; gy1 = cy - 0.5f * l[3];
                gx2 = cx + 0.5f * l[2]; gy2 = cy + 0.5f * l[3];
            }

            float iou1, iou2;
            {
                float ix1 = fmaxf(ax1, gx1), iy1 = fmaxf(ay1, gy1);
                float ix2 = fminf(ax2, gx2), iy2 = fminf(ay2, gy2);
                float inter = fmaxf(ix2 - ix1, 0.0f) * fmaxf(iy2 - iy1, 0.0f);
                float a1 = (ax2 - ax1) * (ay2 - ay1);
                float a2 = (gx2 - gx1) * (gy2 - gy1);
                float denom = a1 + a2 - inter;
                iou1 = (inter > 0.0f) ? inter / denom : 0.0f;
            }
            {
                float ix1 = fmaxf(bx1, gx1), iy1 = fmaxf(by1, gy1);
                float ix2 = fminf(bx2, gx2), iy2 = fminf(by2, gy2);
                float inter = fmaxf(ix2 - ix1, 0.0f) * fmaxf(iy2 - iy1, 0.0f);
                float a1 = (bx2 - bx1) * (by2 - by1);
                float a2 = (gx2 - gx1) * (gy2 - gy1);
                float denom = a1 + a2 - inter;
                iou2 = (inter > 0.0f) ? inter / denom : 0.0f;
            }

            const bool resp1 = (iou1 >= iou2);

            float d0 = p[0] - l[0], d1 = p[1] - l[1];
            float s2 = __builtin_sqrtf(p[2]) - __builtin_sqrtf(l[2]);
            float s3 = __builtin_sqrtf(p[3]) - __builtin_sqrtf(l[3]);
            float coor1 = 5.0f * (d0 * d0 + d1 * d1 + s2 * s2 + s3 * s3);

            float e0 = p[5] - l[5], e1 = p[6] - l[6];
            float t2 = __builtin_sqrtf(p[7]) - __builtin_sqrtf(l[7]);
            float t3 = __builtin_sqrtf(p[8]) - __builtin_sqrtf(l[8]);
            float coor2 = 5.0f * (e0 * e0 + e1 * e1 + t2 * t2 + t3 * t3);

            float o1 = p[4] - iou1; o1 *= o1;
            float o2 = p[9] - iou2; o2 *= o2;

            float coor       = resp1 ? coor1 : coor2;
            float obj_conf   = resp1 ? o1 : o2;
            float noobj_resp = 0.5f * (resp1 ? o2 : o1);
            float noobj_cell = 0.5f * (p[4] * p[4] + p[9] * p[9]);

            const bool obj = (l[4] == 1.0f);
            contrib += obj ? (coor + obj_conf + noobj_resp + cls) : noobj_cell;
        }

        // all compute on buf[cur] done before next iteration overwrites buf[cur^1]'s partner
        __builtin_amdgcn_s_barrier();
    }
    #undef STAGE

    // ---- block reduction: wave shuffle -> LDS -> one partial store ----
    #pragma unroll
    for (int off = 32; off > 0; off >>= 1)
        contrib += __shfl_down(contrib, off, 64);

    __shared__ float wsum[BLK / 64];
    const int lane = tid & 63;
    if (lane == 0) wsum[wid] = contrib;
    __syncthreads();   // vmcnt already 0 here; plain barrier is fine
    if (tid == 0) {
        float bs = 0.0f;
        #pragma unroll
        for (int w = 0; w < BLK / 64; ++w) bs += wsum[w];
        partials[blockIdx.x] = bs;
    }
}

__global__ __launch_bounds__(1024) void yolo_loss_stage2(
    const float* __restrict__ partials,
    float* __restrict__ out,
    int nparts, float inv_B)
{
    float s = (threadIdx.x < nparts) ? partials[threadIdx.x] : 0.0f;

    #pragma unroll
    for (int off = 32; off > 0; off >>= 1)
        s += __shfl_down(s, off, 64);

    __shared__ float wsum[16];
    const int lane = threadIdx.x & 63;
    const int wid  = threadIdx.x >> 6;
    if (lane == 0) wsum[wid] = s;
    __syncthreads();
    if (threadIdx.x == 0) {
        float bs = 0.0f;
        #pragma unroll
        for (int w = 0; w < 16; ++w) bs += wsum[w];
        out[0] = bs * inv_B;
    }
}

extern "C" void kernel_launch(void* const* d_in, const int* in_sizes, int n_in,
                              void* d_out, int out_size, void* d_ws, size_t ws_size,
                              hipStream_t stream) {
    const float4* pred4 = (const float4*)d_in[0];
    const float4* lab4  = (const float4*)d_in[1];
    float* out = (float*)d_out;
    float* partials = (float*)d_ws;

    const int B = in_sizes[0] / IMG_F;     // 16384
    const int npairs = B / K_IMG;          // 8192
    const int grid = (npairs < GRID) ? npairs : GRID;   // 768 persistent blocks

    yolo_loss_stage1<<<grid, BLK, 0, stream>>>(pred4, lab4, partials, npairs);
    yolo_loss_stage2<<<1, 1024, 0, stream>>>(partials, out, grid, 1.0f / (float)B);
}